// Round 11
// baseline (547.073 us; speedup 1.0000x reference)
//
#include <hip/hip_runtime.h>

#define NN 100000
#define NE 3200000
#define NE4 (NE / 4)
#define FIN 128
#define HD 32
#define CD 8
#define NPB 256                      // nodes per bucket (dst >> 8)
#define NBUCK ((NN + NPB - 1) / NPB) // 391
#define CHUNK_B 8192                 // edges per k_bscatter block

typedef unsigned int uint;
typedef unsigned short ushort;

__device__ __forceinline__ float lrelu(float v) { return v > 0.f ? v : 0.01f * v; }
__device__ __forceinline__ uint bf16rne(float x) {
    uint u = __float_as_uint(x);
    return (u + 0x7FFFu + ((u >> 16) & 1u)) >> 16;
}
__device__ __forceinline__ uint pack2(float a, float b) {
    return bf16rne(a) | (bf16rne(b) << 16);
}
__device__ __forceinline__ float lo16(uint v) { return __uint_as_float(v << 16); }
__device__ __forceinline__ float hi16(uint v) { return __uint_as_float(v & 0xFFFF0000u); }

// ---------------- layer 1 dense ----------------

__global__ __launch_bounds__(256) void k_proj128(
    const float* __restrict__ x, const float* __restrict__ Wrel,
    const float* __restrict__ Wroot, const float* __restrict__ b,
    uint* __restrict__ pB, float* __restrict__ R)
{
    __shared__ float Wt[FIN][64];
    for (int idx = threadIdx.x; idx < FIN * 64; idx += 256) {
        int k = idx >> 6, j = idx & 63;
        Wt[k][j] = (j < HD) ? Wrel[j * FIN + k] : Wroot[(j - HD) * FIN + k];
    }
    __syncthreads();
    int n = blockIdx.x * 256 + threadIdx.x;
    if (n >= NN) return;

    float accP[HD], accR[HD];
#pragma unroll
    for (int j = 0; j < HD; ++j) { accP[j] = 0.f; accR[j] = 0.f; }

    const float4* x4 = (const float4*)(x + (size_t)n * FIN);
#pragma unroll 2
    for (int k4 = 0; k4 < FIN / 4; ++k4) {
        float4 xv = x4[k4];
        float xs[4] = {xv.x, xv.y, xv.z, xv.w};
#pragma unroll
        for (int kk = 0; kk < 4; ++kk) {
            float xk = xs[kk];
            int k = k4 * 4 + kk;
#pragma unroll
            for (int j = 0; j < HD; ++j) {
                accP[j] += xk * Wt[k][j];
                accR[j] += xk * Wt[k][j + HD];
            }
        }
    }
    uint4* pp = (uint4*)(pB + (size_t)n * 16);
#pragma unroll
    for (int q = 0; q < 4; ++q)
        pp[q] = make_uint4(pack2(accP[8*q+0], accP[8*q+1]), pack2(accP[8*q+2], accP[8*q+3]),
                           pack2(accP[8*q+4], accP[8*q+5]), pack2(accP[8*q+6], accP[8*q+7]));
    float4* rr = (float4*)(R + (size_t)n * HD);
#pragma unroll
    for (int q = 0; q < HD / 4; ++q)
        rr[q] = make_float4(accR[4*q+0] + b[4*q+0], accR[4*q+1] + b[4*q+1],
                            accR[4*q+2] + b[4*q+2], accR[4*q+3] + b[4*q+3]);
}

// ---------------- bucketed CSR build (R10 structure, unchanged) ----------------

__global__ __launch_bounds__(512) void k_bhist(
    const int* __restrict__ dst, int* __restrict__ bcnt)
{
    __shared__ int lc[NBUCK];
    int t = threadIdx.x;
    for (int i = t; i < NBUCK; i += 512) lc[i] = 0;
    __syncthreads();
    const int4* dst4 = (const int4*)dst;
    for (int i4 = blockIdx.x * 512 + t; i4 < NE4; i4 += gridDim.x * 512) {
        int4 d = dst4[i4];
        atomicAdd(&lc[d.x >> 8], 1);
        atomicAdd(&lc[d.y >> 8], 1);
        atomicAdd(&lc[d.z >> 8], 1);
        atomicAdd(&lc[d.w >> 8], 1);
    }
    __syncthreads();
    for (int i = t; i < NBUCK; i += 512) {
        int c = lc[i];
        if (c) atomicAdd(&bcnt[i], c);
    }
}

__global__ __launch_bounds__(512) void k_bscan(
    const int* __restrict__ bcnt, int* __restrict__ bbase, int* __restrict__ bcur)
{
    __shared__ int s[512];
    int t = threadIdx.x;
    s[t] = (t < NBUCK) ? bcnt[t] : 0;
    __syncthreads();
    for (int off = 1; off < 512; off <<= 1) {
        int a = (t >= off) ? s[t - off] : 0;
        __syncthreads();
        s[t] += a;
        __syncthreads();
    }
    int excl = t ? s[t - 1] : 0;
    if (t < NBUCK) { bbase[t] = excl; bcur[t] = excl; }
    if (t == 0) bbase[NBUCK] = NE;
}

__global__ __launch_bounds__(512) void k_bscatter(
    const int* __restrict__ src, const int* __restrict__ dst, const float* __restrict__ ew,
    int* __restrict__ bcur, int2* __restrict__ tmp)
{
    __shared__ int cnt[NBUCK];
    __shared__ int s[512];
    __shared__ int excl[NBUCK];
    __shared__ int goff[NBUCK];
    __shared__ uint rk[CHUNK_B];      // (bucket << 13) | local_rank
    __shared__ ushort perm[CHUNK_B];
    int t = threadIdx.x;
    int base = blockIdx.x * CHUNK_B;
    int n = min(CHUNK_B, NE - base);

    for (int i = t; i < NBUCK; i += 512) cnt[i] = 0;
    __syncthreads();
    for (int i = t; i < n; i += 512) {
        int b = dst[base + i] >> 8;
        int r = atomicAdd(&cnt[b], 1);
        rk[i] = ((uint)b << 13) | (uint)r;
    }
    __syncthreads();
    int myc = (t < NBUCK) ? cnt[t] : 0;
    s[t] = myc;
    __syncthreads();
    for (int o = 1; o < 512; o <<= 1) {
        int a = (t >= o) ? s[t - o] : 0;
        __syncthreads();
        s[t] += a;
        __syncthreads();
    }
    if (t < NBUCK) {
        excl[t] = s[t] - myc;
        goff[t] = myc ? atomicAdd(&bcur[t], myc) : 0;
    }
    __syncthreads();
    for (int i = t; i < n; i += 512) {
        uint v = rk[i];
        perm[excl[v >> 13] + (v & 8191u)] = (ushort)i;
    }
    __syncthreads();
    for (int j = t; j < n; j += 512) {
        int i = (int)perm[j];
        int d = dst[base + i];
        int b = d >> 8;
        tmp[goff[b] + (j - excl[b])] =
            make_int2(src[base + i] | ((d & 255) << 17), __float_as_int(ew[base + i]));
    }
}

__global__ __launch_bounds__(512) void k_bsort(
    const int* __restrict__ bbase, const int2* __restrict__ tmp,
    int2* __restrict__ epack, int* __restrict__ rowstart)
{
    int b = blockIdx.x, t = threadIdx.x;
    int lo = bbase[b], hi = bbase[b + 1], cnt = hi - lo;
    __shared__ int hist[NPB];
    __shared__ int sc[NPB];
    __shared__ int cur[NPB];
    if (t < NPB) hist[t] = 0;
    __syncthreads();
    for (int i = t; i < cnt; i += 512)
        atomicAdd(&hist[(tmp[lo + i].x >> 17) & 255], 1);
    __syncthreads();
    if (t < NPB) sc[t] = hist[t];
    __syncthreads();
    for (int off = 1; off < NPB; off <<= 1) {
        int a = (t < NPB && t >= off) ? sc[t - off] : 0;
        __syncthreads();
        if (t < NPB) sc[t] += a;
        __syncthreads();
    }
    if (t < NPB) {
        int excl = t ? sc[t - 1] : 0;
        int node = (b << 8) + t;
        if (node < NN) rowstart[node] = lo + excl;
        cur[t] = lo + excl;
    }
    if (b == 0 && t == 0) rowstart[NN] = NE;
    __syncthreads();
    for (int i = t; i < cnt; i += 512) {
        int2 v = tmp[lo + i];
        int l = (v.x >> 17) & 255;
        int pos = atomicAdd(&cur[l], 1);
        epack[pos] = make_int2(v.x & 0x1FFFF, v.y);
    }
}

// ---------------- fused gather + MLP, barrier-free per-wave ----------------

// wave per node: agg = sum w_e*pB1[src]; h = lrelu(agg + R); (all lanes hold h pair)
// lane j<32: rel_j -> pB2 ; lane j>=32: R = root_{j-32} + b2. Single barrier at start.
__global__ __launch_bounds__(256) void k_gMid(
    const int* __restrict__ rowstart, const int2* __restrict__ epack,
    const uint* __restrict__ pB1, float* R,
    const float* __restrict__ Wrel, const float* __restrict__ Wroot,
    const float* __restrict__ b2, uint* __restrict__ pB2)
{
    __shared__ float Ws[HD][64];
    for (int idx = threadIdx.x; idx < HD * 64; idx += 256) {
        int k = idx >> 6, j = idx & 63;
        Ws[k][j] = (j < HD) ? Wrel[j * HD + k] : Wroot[(j - HD) * HD + k];
    }
    __syncthreads();                       // before any divergence: costless

    int wid = (blockIdx.x * 256 + threadIdx.x) >> 6;
    if (wid >= NN) return;
    int lane = threadIdx.x & 63;
    int q = lane >> 4, f2 = lane & 15;
    int rs = rowstart[wid], re = rowstart[wid + 1];

    float a0 = 0.f, a1 = 0.f, b0 = 0.f, b1 = 0.f;
    float c0 = 0.f, c1 = 0.f, d0 = 0.f, d1 = 0.f;
    int e = rs + q;
    for (; e + 12 < re; e += 16) {
        int2 p0 = epack[e];
        int2 p1 = epack[e + 4];
        int2 p2 = epack[e + 8];
        int2 p3 = epack[e + 12];
        uint v0 = pB1[((size_t)p0.x << 4) + f2];
        uint v1 = pB1[((size_t)p1.x << 4) + f2];
        uint v2 = pB1[((size_t)p2.x << 4) + f2];
        uint v3 = pB1[((size_t)p3.x << 4) + f2];
        float w0 = __int_as_float(p0.y), w1 = __int_as_float(p1.y);
        float w2 = __int_as_float(p2.y), w3 = __int_as_float(p3.y);
        a0 += lo16(v0) * w0; a1 += hi16(v0) * w0;
        b0 += lo16(v1) * w1; b1 += hi16(v1) * w1;
        c0 += lo16(v2) * w2; c1 += hi16(v2) * w2;
        d0 += lo16(v3) * w3; d1 += hi16(v3) * w3;
    }
    for (; e < re; e += 4) {
        int2 p0 = epack[e];
        uint v0 = pB1[((size_t)p0.x << 4) + f2];
        float w0 = __int_as_float(p0.y);
        a0 += lo16(v0) * w0; a1 += hi16(v0) * w0;
    }
    a0 += b0 + c0 + d0; a1 += b1 + c1 + d1;
    a0 += __shfl_xor(a0, 16); a1 += __shfl_xor(a1, 16);
    a0 += __shfl_xor(a0, 32); a1 += __shfl_xor(a1, 32);   // all lanes: full sums for f2

    float2 rv = *(const float2*)(R + (size_t)wid * HD + 2 * f2);
    float h0 = lrelu(a0 + rv.x);
    float h1 = lrelu(a1 + rv.y);

    // per-lane MLP output j = lane; h broadcast from lane k>>1
    int j = lane;
    float acc = 0.f;
#pragma unroll
    for (int k = 0; k < HD; k += 2) {
        float ha = __shfl(h0, k >> 1);
        float hb = __shfl(h1, k >> 1);
        acc += ha * Ws[k][j] + hb * Ws[k + 1][j];
    }
    float other = __shfl_xor(acc, 1);
    if (j < HD) {
        if (!(j & 1)) pB2[(size_t)wid * 16 + (j >> 1)] = pack2(acc, other);
    } else {
        R[(size_t)wid * HD + (j - HD)] = acc + b2[j - HD];
    }
}

// same pattern for layer 3: outputs 8 rel (p3B) + 8 root (+b3 -> out)
__global__ __launch_bounds__(256) void k_gLast(
    const int* __restrict__ rowstart, const int2* __restrict__ epack,
    const uint* __restrict__ pB2, const float* __restrict__ R,
    const float* __restrict__ Wrel, const float* __restrict__ Wroot,
    const float* __restrict__ b3, uint* __restrict__ p3B, float* __restrict__ out)
{
    __shared__ float Ws[HD][16];
    for (int idx = threadIdx.x; idx < HD * 16; idx += 256) {
        int k = idx >> 4, j = idx & 15;
        Ws[k][j] = (j < CD) ? Wrel[j * HD + k] : Wroot[(j - CD) * HD + k];
    }
    __syncthreads();

    int wid = (blockIdx.x * 256 + threadIdx.x) >> 6;
    if (wid >= NN) return;
    int lane = threadIdx.x & 63;
    int q = lane >> 4, f2 = lane & 15;
    int rs = rowstart[wid], re = rowstart[wid + 1];

    float a0 = 0.f, a1 = 0.f, b0 = 0.f, b1 = 0.f;
    float c0 = 0.f, c1 = 0.f, d0 = 0.f, d1 = 0.f;
    int e = rs + q;
    for (; e + 12 < re; e += 16) {
        int2 p0 = epack[e];
        int2 p1 = epack[e + 4];
        int2 p2 = epack[e + 8];
        int2 p3 = epack[e + 12];
        uint v0 = pB2[((size_t)p0.x << 4) + f2];
        uint v1 = pB2[((size_t)p1.x << 4) + f2];
        uint v2 = pB2[((size_t)p2.x << 4) + f2];
        uint v3 = pB2[((size_t)p3.x << 4) + f2];
        float w0 = __int_as_float(p0.y), w1 = __int_as_float(p1.y);
        float w2 = __int_as_float(p2.y), w3 = __int_as_float(p3.y);
        a0 += lo16(v0) * w0; a1 += hi16(v0) * w0;
        b0 += lo16(v1) * w1; b1 += hi16(v1) * w1;
        c0 += lo16(v2) * w2; c1 += hi16(v2) * w2;
        d0 += lo16(v3) * w3; d1 += hi16(v3) * w3;
    }
    for (; e < re; e += 4) {
        int2 p0 = epack[e];
        uint v0 = pB2[((size_t)p0.x << 4) + f2];
        float w0 = __int_as_float(p0.y);
        a0 += lo16(v0) * w0; a1 += hi16(v0) * w0;
    }
    a0 += b0 + c0 + d0; a1 += b1 + c1 + d1;
    a0 += __shfl_xor(a0, 16); a1 += __shfl_xor(a1, 16);
    a0 += __shfl_xor(a0, 32); a1 += __shfl_xor(a1, 32);

    float2 rv = *(const float2*)(R + (size_t)wid * HD + 2 * f2);
    float h0 = lrelu(a0 + rv.x);
    float h1 = lrelu(a1 + rv.y);

    int j = lane;
    float acc = 0.f;
#pragma unroll
    for (int k = 0; k < HD; k += 2) {
        float ha = __shfl(h0, k >> 1);
        float hb = __shfl(h1, k >> 1);
        if (j < 16) acc += ha * Ws[k][j] + hb * Ws[k + 1][j];
    }
    float other = __shfl_xor(acc, 1);
    if (j < CD) {
        if (!(j & 1)) p3B[(size_t)wid * 4 + (j >> 1)] = pack2(acc, other);
    } else if (j < 16) {
        out[(size_t)wid * CD + (j - CD)] = acc + b3[j - CD];
    }
}

// wave per node; RMW aggregated rel-part into out
__global__ __launch_bounds__(256) void k_gather8(
    const int* __restrict__ rowstart, const int2* __restrict__ epack,
    const uint* __restrict__ p3B, float* __restrict__ out)
{
    int wid = (blockIdx.x * 256 + threadIdx.x) >> 6;
    if (wid >= NN) return;
    int lane = threadIdx.x & 63;
    int q = lane >> 2, f2 = lane & 3;
    int rs = rowstart[wid], re = rowstart[wid + 1];

    float a0 = 0.f, a1 = 0.f, b0 = 0.f, b1 = 0.f;
    int e = rs + q;
    for (; e + 16 < re; e += 32) {
        int2 p0 = epack[e];
        int2 p1 = epack[e + 16];
        uint v0 = p3B[((size_t)p0.x << 2) + f2];
        uint v1 = p3B[((size_t)p1.x << 2) + f2];
        float w0 = __int_as_float(p0.y), w1 = __int_as_float(p1.y);
        a0 += lo16(v0) * w0; a1 += hi16(v0) * w0;
        b0 += lo16(v1) * w1; b1 += hi16(v1) * w1;
    }
    for (; e < re; e += 16) {
        int2 p0 = epack[e];
        uint v0 = p3B[((size_t)p0.x << 2) + f2];
        float w0 = __int_as_float(p0.y);
        a0 += lo16(v0) * w0; a1 += hi16(v0) * w0;
    }
    a0 += b0; a1 += b1;
    a0 += __shfl_xor(a0, 4);  a1 += __shfl_xor(a1, 4);
    a0 += __shfl_xor(a0, 8);  a1 += __shfl_xor(a1, 8);
    a0 += __shfl_xor(a0, 16); a1 += __shfl_xor(a1, 16);
    a0 += __shfl_xor(a0, 32); a1 += __shfl_xor(a1, 32);
    if (lane < 4) {
        float2* o2 = (float2*)(out + (size_t)wid * CD + 2 * f2);
        float2 t = *o2;
        t.x += a0; t.y += a1;
        *o2 = t;
    }
}

// ---------------- launch ----------------

extern "C" void kernel_launch(void* const* d_in, const int* in_sizes, int n_in,
                              void* d_out, int out_size, void* d_ws, size_t ws_size,
                              hipStream_t stream)
{
    const float* x      = (const float*)d_in[0];
    const int*   ei     = (const int*)d_in[1];
    const float* ew     = (const float*)d_in[2];
    const float* W1rel  = (const float*)d_in[3];
    const float* b1     = (const float*)d_in[4];
    const float* W1root = (const float*)d_in[5];
    const float* W2rel  = (const float*)d_in[6];
    const float* b2     = (const float*)d_in[7];
    const float* W2root = (const float*)d_in[8];
    const float* W3rel  = (const float*)d_in[9];
    const float* b3     = (const float*)d_in[10];
    const float* W3root = (const float*)d_in[11];
    float* out = (float*)d_out;

    const int* src = ei;
    const int* dst = ei + NE;

    // flat workspace ~79 MB (no aliasing; G eliminated)
    char* ws = (char*)d_ws;
    int2*  epack    = (int2*)ws;   ws += (size_t)NE * sizeof(int2);   // 25.6 MB
    int2*  tmp      = (int2*)ws;   ws += (size_t)NE * sizeof(int2);   // 25.6 MB
    float* R        = (float*)ws;  ws += (size_t)NN * HD * 4;         // 12.8 MB
    uint*  pB1      = (uint*)ws;   ws += (size_t)NN * 16 * 4;         // 6.4 MB
    uint*  pB2      = (uint*)ws;   ws += (size_t)NN * 16 * 4;         // 6.4 MB
    uint*  p3B      = (uint*)ws;   ws += (size_t)NN * 4 * 4;          // 1.6 MB
    int*   rowstart = (int*)ws;    ws += (size_t)(NN + 1) * 4;
    int*   bcnt     = (int*)ws;    ws += (size_t)NBUCK * 4;
    int*   bbase    = (int*)ws;    ws += (size_t)(NBUCK + 1) * 4;
    int*   bcur     = (int*)ws;

    const int nodeBlocks = (NN + 255) / 256;
    const int waveBlocks = (NN + 3) / 4;                   // 25000 exact
    const int scatBlocks = (NE + CHUNK_B - 1) / CHUNK_B;   // 391

    // --- CSR build ---
    hipMemsetAsync(bcnt, 0, (size_t)NBUCK * 4, stream);
    k_bhist<<<512, 512, 0, stream>>>(dst, bcnt);
    k_bscan<<<1, 512, 0, stream>>>(bcnt, bbase, bcur);
    k_bscatter<<<scatBlocks, 512, 0, stream>>>(src, dst, ew, bcur, tmp);
    k_bsort<<<NBUCK, 512, 0, stream>>>(bbase, tmp, epack, rowstart);

    // --- layer 1 dense ---
    k_proj128<<<nodeBlocks, 256, 0, stream>>>(x, W1rel, W1root, b1, pB1, R);
    // --- gather1 + layer2 (fused, barrier-free) ---
    k_gMid<<<waveBlocks, 256, 0, stream>>>(rowstart, epack, pB1, R, W2rel, W2root, b2, pB2);
    // --- gather2 + layer3 (fused, barrier-free) ---
    k_gLast<<<waveBlocks, 256, 0, stream>>>(rowstart, epack, pB2, R, W3rel, W3root, b3, p3B, out);
    // --- final aggregation into out ---
    k_gather8<<<waveBlocks, 256, 0, stream>>>(rowstart, epack, p3B, out);
}

// Round 12
// 447.103 us; speedup vs baseline: 1.2236x; 1.2236x over previous
//
#include <hip/hip_runtime.h>

#define NN 100000
#define NE 3200000
#define NE4 (NE / 4)
#define FIN 128
#define HD 32
#define CD 8
#define NPB 256                      // nodes per bucket (dst >> 8)
#define NBUCK ((NN + NPB - 1) / NPB) // 391
#define CHUNK_B 8192                 // edges per k_bscatter block
#define BCAP 10240                   // k_bsort in-LDS capacity (mean 8184, 22 sigma headroom)

typedef unsigned int uint;
typedef unsigned short ushort;

__device__ __forceinline__ float lrelu(float v) { return v > 0.f ? v : 0.01f * v; }
__device__ __forceinline__ uint bf16rne(float x) {
    uint u = __float_as_uint(x);
    return (u + 0x7FFFu + ((u >> 16) & 1u)) >> 16;
}
__device__ __forceinline__ uint pack2(float a, float b) {
    return bf16rne(a) | (bf16rne(b) << 16);
}
__device__ __forceinline__ float lo16(uint v) { return __uint_as_float(v << 16); }
__device__ __forceinline__ float hi16(uint v) { return __uint_as_float(v & 0xFFFF0000u); }

// ---------------- layer 1 dense ----------------

__global__ __launch_bounds__(256) void k_proj128(
    const float* __restrict__ x, const float* __restrict__ Wrel,
    const float* __restrict__ Wroot, const float* __restrict__ b,
    uint* __restrict__ pB, float* __restrict__ R)
{
    __shared__ float Wt[FIN][64];
    for (int idx = threadIdx.x; idx < FIN * 64; idx += 256) {
        int k = idx >> 6, j = idx & 63;
        Wt[k][j] = (j < HD) ? Wrel[j * FIN + k] : Wroot[(j - HD) * FIN + k];
    }
    __syncthreads();
    int n = blockIdx.x * 256 + threadIdx.x;
    if (n >= NN) return;

    float accP[HD], accR[HD];
#pragma unroll
    for (int j = 0; j < HD; ++j) { accP[j] = 0.f; accR[j] = 0.f; }

    const float4* x4 = (const float4*)(x + (size_t)n * FIN);
#pragma unroll 2
    for (int k4 = 0; k4 < FIN / 4; ++k4) {
        float4 xv = x4[k4];
        float xs[4] = {xv.x, xv.y, xv.z, xv.w};
#pragma unroll
        for (int kk = 0; kk < 4; ++kk) {
            float xk = xs[kk];
            int k = k4 * 4 + kk;
#pragma unroll
            for (int j = 0; j < HD; ++j) {
                accP[j] += xk * Wt[k][j];
                accR[j] += xk * Wt[k][j + HD];
            }
        }
    }
    uint4* pp = (uint4*)(pB + (size_t)n * 16);
#pragma unroll
    for (int q = 0; q < 4; ++q)
        pp[q] = make_uint4(pack2(accP[8*q+0], accP[8*q+1]), pack2(accP[8*q+2], accP[8*q+3]),
                           pack2(accP[8*q+4], accP[8*q+5]), pack2(accP[8*q+6], accP[8*q+7]));
    float4* rr = (float4*)(R + (size_t)n * HD);
#pragma unroll
    for (int q = 0; q < HD / 4; ++q)
        rr[q] = make_float4(accR[4*q+0] + b[4*q+0], accR[4*q+1] + b[4*q+1],
                            accR[4*q+2] + b[4*q+2], accR[4*q+3] + b[4*q+3]);
}

// ---------------- layer 2/3 dense (unfused, proven) ----------------

__global__ __launch_bounds__(256) void k_mid(
    const float* __restrict__ G, const float* R_in,
    const float* __restrict__ Wrel, const float* __restrict__ Wroot,
    const float* __restrict__ b,
    uint* __restrict__ pB, float* R_out)
{
    __shared__ float Ws[HD][64];
    for (int idx = threadIdx.x; idx < HD * 64; idx += 256) {
        int k = idx >> 6, j = idx & 63;
        Ws[k][j] = (j < HD) ? Wrel[j * HD + k] : Wroot[(j - HD) * HD + k];
    }
    __syncthreads();
    int n = blockIdx.x * 256 + threadIdx.x;
    if (n >= NN) return;

    float h[HD];
    const float4* av = (const float4*)(G + (size_t)n * HD);
    const float4* rv = (const float4*)(R_in + (size_t)n * HD);
#pragma unroll
    for (int q = 0; q < HD / 4; ++q) {
        float4 a = av[q], r_ = rv[q];
        h[4*q+0] = lrelu(a.x + r_.x);
        h[4*q+1] = lrelu(a.y + r_.y);
        h[4*q+2] = lrelu(a.z + r_.z);
        h[4*q+3] = lrelu(a.w + r_.w);
    }
    float accP[HD], accR[HD];
#pragma unroll
    for (int j = 0; j < HD; ++j) { accP[j] = 0.f; accR[j] = 0.f; }
#pragma unroll 4
    for (int k = 0; k < HD; ++k) {
        float hk = h[k];
#pragma unroll
        for (int j = 0; j < HD; ++j) {
            accP[j] += hk * Ws[k][j];
            accR[j] += hk * Ws[k][j + HD];
        }
    }
    uint4* pp = (uint4*)(pB + (size_t)n * 16);
#pragma unroll
    for (int q = 0; q < 4; ++q)
        pp[q] = make_uint4(pack2(accP[8*q+0], accP[8*q+1]), pack2(accP[8*q+2], accP[8*q+3]),
                           pack2(accP[8*q+4], accP[8*q+5]), pack2(accP[8*q+6], accP[8*q+7]));
    float4* rr = (float4*)(R_out + (size_t)n * HD);
#pragma unroll
    for (int q = 0; q < HD / 4; ++q)
        rr[q] = make_float4(accR[4*q+0] + b[4*q+0], accR[4*q+1] + b[4*q+1],
                            accR[4*q+2] + b[4*q+2], accR[4*q+3] + b[4*q+3]);
}

__global__ __launch_bounds__(256) void k_last(
    const float* __restrict__ G, const float* __restrict__ R,
    const float* __restrict__ Wrel, const float* __restrict__ Wroot,
    const float* __restrict__ b,
    uint* __restrict__ p3B, float* __restrict__ out)
{
    __shared__ float Ws[HD][16];
    for (int idx = threadIdx.x; idx < HD * 16; idx += 256) {
        int k = idx >> 4, j = idx & 15;
        Ws[k][j] = (j < CD) ? Wrel[j * HD + k] : Wroot[(j - CD) * HD + k];
    }
    __syncthreads();
    int n = blockIdx.x * 256 + threadIdx.x;
    if (n >= NN) return;

    float h[HD];
    const float4* av = (const float4*)(G + (size_t)n * HD);
    const float4* rv = (const float4*)(R + (size_t)n * HD);
#pragma unroll
    for (int q = 0; q < HD / 4; ++q) {
        float4 a = av[q], r_ = rv[q];
        h[4*q+0] = lrelu(a.x + r_.x);
        h[4*q+1] = lrelu(a.y + r_.y);
        h[4*q+2] = lrelu(a.z + r_.z);
        h[4*q+3] = lrelu(a.w + r_.w);
    }
    float accP[CD], accR[CD];
#pragma unroll
    for (int j = 0; j < CD; ++j) { accP[j] = 0.f; accR[j] = 0.f; }
#pragma unroll
    for (int k = 0; k < HD; ++k) {
        float hk = h[k];
#pragma unroll
        for (int j = 0; j < CD; ++j) {
            accP[j] += hk * Ws[k][j];
            accR[j] += hk * Ws[k][j + CD];
        }
    }
    uint4* pp = (uint4*)(p3B + (size_t)n * 4);
    pp[0] = make_uint4(pack2(accP[0], accP[1]), pack2(accP[2], accP[3]),
                       pack2(accP[4], accP[5]), pack2(accP[6], accP[7]));
    float4* oo = (float4*)(out + (size_t)n * CD);
    oo[0] = make_float4(accR[0] + b[0], accR[1] + b[1], accR[2] + b[2], accR[3] + b[3]);
    oo[1] = make_float4(accR[4] + b[4], accR[5] + b[5], accR[6] + b[6], accR[7] + b[7]);
}

// ---------------- bucketed CSR build ----------------

__global__ __launch_bounds__(512) void k_bhist(
    const int* __restrict__ dst, int* __restrict__ bcnt)
{
    __shared__ int lc[NBUCK];
    int t = threadIdx.x;
    for (int i = t; i < NBUCK; i += 512) lc[i] = 0;
    __syncthreads();
    const int4* dst4 = (const int4*)dst;
    for (int i4 = blockIdx.x * 512 + t; i4 < NE4; i4 += gridDim.x * 512) {
        int4 d = dst4[i4];
        atomicAdd(&lc[d.x >> 8], 1);
        atomicAdd(&lc[d.y >> 8], 1);
        atomicAdd(&lc[d.z >> 8], 1);
        atomicAdd(&lc[d.w >> 8], 1);
    }
    __syncthreads();
    for (int i = t; i < NBUCK; i += 512) {
        int c = lc[i];
        if (c) atomicAdd(&bcnt[i], c);
    }
}

__global__ __launch_bounds__(512) void k_bscan(
    const int* __restrict__ bcnt, int* __restrict__ bbase, int* __restrict__ bcur)
{
    __shared__ int s[512];
    int t = threadIdx.x;
    s[t] = (t < NBUCK) ? bcnt[t] : 0;
    __syncthreads();
    for (int off = 1; off < 512; off <<= 1) {
        int a = (t >= off) ? s[t - off] : 0;
        __syncthreads();
        s[t] += a;
        __syncthreads();
    }
    int excl = t ? s[t - 1] : 0;
    if (t < NBUCK) { bbase[t] = excl; bcur[t] = excl; }
    if (t == 0) bbase[NBUCK] = NE;
}

// single-rank-pass staged bucket-scatter (R10-proven): coalesced tmp writes
__global__ __launch_bounds__(512) void k_bscatter(
    const int* __restrict__ src, const int* __restrict__ dst, const float* __restrict__ ew,
    int* __restrict__ bcur, int2* __restrict__ tmp)
{
    __shared__ int cnt[NBUCK];
    __shared__ int s[512];
    __shared__ int excl[NBUCK];
    __shared__ int goff[NBUCK];
    __shared__ uint rk[CHUNK_B];      // (bucket << 13) | local_rank
    __shared__ ushort perm[CHUNK_B];
    int t = threadIdx.x;
    int base = blockIdx.x * CHUNK_B;
    int n = min(CHUNK_B, NE - base);

    for (int i = t; i < NBUCK; i += 512) cnt[i] = 0;
    __syncthreads();
    for (int i = t; i < n; i += 512) {
        int b = dst[base + i] >> 8;
        int r = atomicAdd(&cnt[b], 1);
        rk[i] = ((uint)b << 13) | (uint)r;
    }
    __syncthreads();
    int myc = (t < NBUCK) ? cnt[t] : 0;
    s[t] = myc;
    __syncthreads();
    for (int o = 1; o < 512; o <<= 1) {
        int a = (t >= o) ? s[t - o] : 0;
        __syncthreads();
        s[t] += a;
        __syncthreads();
    }
    if (t < NBUCK) {
        excl[t] = s[t] - myc;
        goff[t] = myc ? atomicAdd(&bcur[t], myc) : 0;
    }
    __syncthreads();
    for (int i = t; i < n; i += 512) {
        uint v = rk[i];
        perm[excl[v >> 13] + (v & 8191u)] = (ushort)i;
    }
    __syncthreads();
    for (int j = t; j < n; j += 512) {
        int i = (int)perm[j];
        int d = dst[base + i];
        int b = d >> 8;
        tmp[goff[b] + (j - excl[b])] =
            make_int2(src[base + i] | ((d & 255) << 17), __float_as_int(ew[base + i]));
    }
}

// perm-staged in-bucket node sort: coalesced epack writes (same recipe as bscatter)
__global__ __launch_bounds__(512) void k_bsort(
    const int* __restrict__ bbase, const int2* __restrict__ tmp,
    int2* __restrict__ epack, int* __restrict__ rowstart)
{
    __shared__ int hist[NPB];
    __shared__ int sc[NPB];
    __shared__ int excl[NPB];
    __shared__ int cur[NPB];
    __shared__ uint rk[BCAP];
    __shared__ ushort perm[BCAP];
    int b = blockIdx.x, t = threadIdx.x;
    int lo = bbase[b], hi = bbase[b + 1], cnt = hi - lo;

    if (t < NPB) hist[t] = 0;
    __syncthreads();
    if (cnt <= BCAP) {
        // rank pass
        for (int i = t; i < cnt; i += 512) {
            int l = (tmp[lo + i].x >> 17) & 255;
            int r = atomicAdd(&hist[l], 1);
            rk[i] = ((uint)l << 14) | (uint)r;
        }
        __syncthreads();
        if (t < NPB) sc[t] = hist[t];
        __syncthreads();
        for (int off = 1; off < NPB; off <<= 1) {
            int a = (t < NPB && t >= off) ? sc[t - off] : 0;
            __syncthreads();
            if (t < NPB) sc[t] += a;
            __syncthreads();
        }
        if (t < NPB) {
            int ex = t ? sc[t - 1] : 0;
            excl[t] = ex;
            int node = (b << 8) + t;
            if (node < NN) rowstart[node] = lo + ex;
        }
        if (b == 0 && t == 0) rowstart[NN] = NE;
        __syncthreads();
        for (int i = t; i < cnt; i += 512) {
            uint v = rk[i];
            perm[excl[v >> 14] + (v & 16383u)] = (ushort)i;
        }
        __syncthreads();
        // coalesced: consecutive j -> consecutive epack addresses
        for (int j = t; j < cnt; j += 512) {
            int2 v = tmp[lo + (int)perm[j]];
            epack[lo + j] = make_int2(v.x & 0x1FFFF, v.y);
        }
    } else {
        // statistically unreachable fallback: scattered writes
        for (int i = t; i < cnt; i += 512)
            atomicAdd(&hist[(tmp[lo + i].x >> 17) & 255], 1);
        __syncthreads();
        if (t < NPB) sc[t] = hist[t];
        __syncthreads();
        for (int off = 1; off < NPB; off <<= 1) {
            int a = (t < NPB && t >= off) ? sc[t - off] : 0;
            __syncthreads();
            if (t < NPB) sc[t] += a;
            __syncthreads();
        }
        if (t < NPB) {
            int ex = t ? sc[t - 1] : 0;
            int node = (b << 8) + t;
            if (node < NN) rowstart[node] = lo + ex;
            cur[t] = lo + ex;
        }
        if (b == 0 && t == 0) rowstart[NN] = NE;
        __syncthreads();
        for (int i = t; i < cnt; i += 512) {
            int2 v = tmp[lo + i];
            int l = (v.x >> 17) & 255;
            int pos = atomicAdd(&cur[l], 1);
            epack[pos] = make_int2(v.x & 0x1FFFF, v.y);
        }
    }
}

// ---------------- register-accumulate gathers ----------------

// wave per node; lane = q(0..3)*16 + f2(0..15); 16 edges/wave in flight
__global__ __launch_bounds__(256) void k_gather32(
    const int* __restrict__ rowstart, const int2* __restrict__ epack,
    const uint* __restrict__ pB, float* __restrict__ G)
{
    int wid = (blockIdx.x * 256 + threadIdx.x) >> 6;
    if (wid >= NN) return;
    int lane = threadIdx.x & 63;
    int q = lane >> 4, f2 = lane & 15;
    int rs = rowstart[wid], re = rowstart[wid + 1];

    float a0 = 0.f, a1 = 0.f, b0 = 0.f, b1 = 0.f;
    float c0 = 0.f, c1 = 0.f, d0 = 0.f, d1 = 0.f;
    int e = rs + q;
    for (; e + 12 < re; e += 16) {
        int2 p0 = epack[e];
        int2 p1 = epack[e + 4];
        int2 p2 = epack[e + 8];
        int2 p3 = epack[e + 12];
        uint v0 = pB[((size_t)p0.x << 4) + f2];
        uint v1 = pB[((size_t)p1.x << 4) + f2];
        uint v2 = pB[((size_t)p2.x << 4) + f2];
        uint v3 = pB[((size_t)p3.x << 4) + f2];
        float w0 = __int_as_float(p0.y), w1 = __int_as_float(p1.y);
        float w2 = __int_as_float(p2.y), w3 = __int_as_float(p3.y);
        a0 += lo16(v0) * w0; a1 += hi16(v0) * w0;
        b0 += lo16(v1) * w1; b1 += hi16(v1) * w1;
        c0 += lo16(v2) * w2; c1 += hi16(v2) * w2;
        d0 += lo16(v3) * w3; d1 += hi16(v3) * w3;
    }
    for (; e < re; e += 4) {
        int2 p0 = epack[e];
        uint v0 = pB[((size_t)p0.x << 4) + f2];
        float w0 = __int_as_float(p0.y);
        a0 += lo16(v0) * w0; a1 += hi16(v0) * w0;
    }
    a0 += b0 + c0 + d0; a1 += b1 + c1 + d1;
    a0 += __shfl_xor(a0, 16); a1 += __shfl_xor(a1, 16);
    a0 += __shfl_xor(a0, 32); a1 += __shfl_xor(a1, 32);
    if (lane < 16) {
        float2* g2 = (float2*)(G + (size_t)wid * HD + 2 * f2);
        *g2 = make_float2(a0, a1);
    }
}

__global__ __launch_bounds__(256) void k_gather8(
    const int* __restrict__ rowstart, const int2* __restrict__ epack,
    const uint* __restrict__ p3B, float* __restrict__ out)
{
    int wid = (blockIdx.x * 256 + threadIdx.x) >> 6;
    if (wid >= NN) return;
    int lane = threadIdx.x & 63;
    int q = lane >> 2, f2 = lane & 3;
    int rs = rowstart[wid], re = rowstart[wid + 1];

    float a0 = 0.f, a1 = 0.f, b0 = 0.f, b1 = 0.f;
    int e = rs + q;
    for (; e + 16 < re; e += 32) {
        int2 p0 = epack[e];
        int2 p1 = epack[e + 16];
        uint v0 = p3B[((size_t)p0.x << 2) + f2];
        uint v1 = p3B[((size_t)p1.x << 2) + f2];
        float w0 = __int_as_float(p0.y), w1 = __int_as_float(p1.y);
        a0 += lo16(v0) * w0; a1 += hi16(v0) * w0;
        b0 += lo16(v1) * w1; b1 += hi16(v1) * w1;
    }
    for (; e < re; e += 16) {
        int2 p0 = epack[e];
        uint v0 = p3B[((size_t)p0.x << 2) + f2];
        float w0 = __int_as_float(p0.y);
        a0 += lo16(v0) * w0; a1 += hi16(v0) * w0;
    }
    a0 += b0; a1 += b1;
    a0 += __shfl_xor(a0, 4);  a1 += __shfl_xor(a1, 4);
    a0 += __shfl_xor(a0, 8);  a1 += __shfl_xor(a1, 8);
    a0 += __shfl_xor(a0, 16); a1 += __shfl_xor(a1, 16);
    a0 += __shfl_xor(a0, 32); a1 += __shfl_xor(a1, 32);
    if (lane < 4) {
        float2* o2 = (float2*)(out + (size_t)wid * CD + 2 * f2);
        float2 t = *o2;
        t.x += a0; t.y += a1;
        *o2 = t;
    }
}

// ---------------- launch ----------------

extern "C" void kernel_launch(void* const* d_in, const int* in_sizes, int n_in,
                              void* d_out, int out_size, void* d_ws, size_t ws_size,
                              hipStream_t stream)
{
    const float* x      = (const float*)d_in[0];
    const int*   ei     = (const int*)d_in[1];
    const float* ew     = (const float*)d_in[2];
    const float* W1rel  = (const float*)d_in[3];
    const float* b1     = (const float*)d_in[4];
    const float* W1root = (const float*)d_in[5];
    const float* W2rel  = (const float*)d_in[6];
    const float* b2     = (const float*)d_in[7];
    const float* W2root = (const float*)d_in[8];
    const float* W3rel  = (const float*)d_in[9];
    const float* b3     = (const float*)d_in[10];
    const float* W3root = (const float*)d_in[11];
    float* out = (float*)d_out;

    const int* src = ei;
    const int* dst = ei + NE;

    // workspace ~60 MB; tmp (dead after k_bsort) aliases G+R
    char* ws = (char*)d_ws;
    int2*  epack    = (int2*)ws;   ws += (size_t)NE * sizeof(int2);   // 25.6 MB
    char*  unionA   = ws;          ws += (size_t)NE * sizeof(int2);   // 25.6 MB (tmp | G+R)
    uint*  pB       = (uint*)ws;   ws += (size_t)NN * 16 * 4;         // 6.4 MB
    uint*  p3B      = (uint*)ws;   ws += (size_t)NN * 4 * 4;          // 1.6 MB
    int*   rowstart = (int*)ws;    ws += (size_t)(NN + 1) * 4;
    int*   bcnt     = (int*)ws;    ws += (size_t)NBUCK * 4;
    int*   bbase    = (int*)ws;    ws += (size_t)(NBUCK + 1) * 4;
    int*   bcur     = (int*)ws;

    int2*  tmp = (int2*)unionA;
    float* G   = (float*)unionA;
    float* R   = G + (size_t)NN * HD;

    const int nodeBlocks = (NN + 255) / 256;
    const int waveBlocks = (NN + 3) / 4;
    const int scatBlocks = (NE + CHUNK_B - 1) / CHUNK_B;   // 391

    // --- CSR build ---
    hipMemsetAsync(bcnt, 0, (size_t)NBUCK * 4, stream);
    k_bhist<<<512, 512, 0, stream>>>(dst, bcnt);
    k_bscan<<<1, 512, 0, stream>>>(bcnt, bbase, bcur);
    k_bscatter<<<scatBlocks, 512, 0, stream>>>(src, dst, ew, bcur, tmp);
    k_bsort<<<NBUCK, 512, 0, stream>>>(bbase, tmp, epack, rowstart);

    // --- layer 1 ---
    k_proj128<<<nodeBlocks, 256, 0, stream>>>(x, W1rel, W1root, b1, pB, R);
    k_gather32<<<waveBlocks, 256, 0, stream>>>(rowstart, epack, pB, G);
    // --- layer 2 ---
    k_mid<<<nodeBlocks, 256, 0, stream>>>(G, R, W2rel, W2root, b2, pB, R);
    k_gather32<<<waveBlocks, 256, 0, stream>>>(rowstart, epack, pB, G);
    // --- layer 3 ---
    k_last<<<nodeBlocks, 256, 0, stream>>>(G, R, W3rel, W3root, b3, p3B, out);
    k_gather8<<<waveBlocks, 256, 0, stream>>>(rowstart, epack, p3B, out);
}